// Round 1
// baseline (2887.385 us; speedup 1.0000x reference)
//
#include <hip/hip_runtime.h>
#include <hip/hip_bf16.h>

#define B_ 4
#define N_ 4096
#define C_ 256
#define P_ 1024
#define S_ 64
#define O1_ 256
#define CIN_ 259   // 3 + C
#define XST 68     // LDS row stride (floats), 16B-aligned rows, bank-spread

__device__ __forceinline__ float rn_mul(float a, float b){ return __fmul_rn(a,b); }
__device__ __forceinline__ float rn_add(float a, float b){ return __fadd_rn(a,b); }
__device__ __forceinline__ float rn_sub(float a, float b){ return __fsub_rn(a,b); }

__device__ __forceinline__ unsigned long long shflxor_u64(unsigned long long v, int m){
  unsigned lo = (unsigned)__shfl_xor((int)(unsigned)(v & 0xFFFFFFFFull), m, 64);
  unsigned hi = (unsigned)__shfl_xor((int)(unsigned)(v >> 32), m, 64);
  return ((unsigned long long)hi << 32) | (unsigned long long)lo;
}

// ---------------- FPS: one block per batch, exact fp32 semantics ----------------
__global__ __launch_bounds__(1024) void fps_kernel(const float* __restrict__ xyz,
                                                   float* __restrict__ newXyz)
{
  const int b = blockIdx.x;
  const int t = threadIdx.x;
  const int lane = t & 63, wid = t >> 6;
  __shared__ float xl[N_*3];
  __shared__ unsigned long long wred[16];
  __shared__ int sFar;
  const float* xb = xyz + (size_t)b*N_*3;
  for (int i = t; i < N_*3; i += 1024) xl[i] = xb[i];
  __syncthreads();
  float px[4], py[4], pz[4], dist[4];
  #pragma unroll
  for (int j=0;j<4;j++){
    int n = t*4 + j;
    px[j] = xl[n*3+0]; py[j] = xl[n*3+1]; pz[j] = xl[n*3+2];
    dist[j] = 1e10f;
  }
  int far = 0;
  for (int it=0; it<P_; ++it){
    float cx = xl[far*3+0], cy = xl[far*3+1], cz = xl[far*3+2];
    if (t == 0){
      float* nz = newXyz + ((size_t)b*P_ + it)*3;
      nz[0]=cx; nz[1]=cy; nz[2]=cz;
    }
    unsigned long long best = 0;
    #pragma unroll
    for (int j=0;j<4;j++){
      float dx = rn_sub(px[j],cx), dy = rn_sub(py[j],cy), dz = rn_sub(pz[j],cz);
      float d = rn_add(rn_add(rn_mul(dx,dx), rn_mul(dy,dy)), rn_mul(dz,dz));
      float nd = fminf(dist[j], d);
      dist[j] = nd;
      unsigned long long pk = ((unsigned long long)__float_as_uint(nd) << 32)
                            | (unsigned long long)(unsigned)(~(unsigned)(t*4+j));
      best = pk > best ? pk : best;
    }
    #pragma unroll
    for (int m = 32; m >= 1; m >>= 1){
      unsigned long long o = shflxor_u64(best, m);
      best = o > best ? o : best;
    }
    if (lane == 0) wred[wid] = best;
    __syncthreads();
    if (t < 64){
      unsigned long long v = wred[t & 15];
      #pragma unroll
      for (int m = 8; m >= 1; m >>= 1){
        unsigned long long o = shflxor_u64(v, m);
        v = o > v ? o : v;
      }
      if (t == 0) sFar = (int)(~(unsigned)(v & 0xFFFFFFFFull));
    }
    __syncthreads();
    far = sFar;
  }
}

// ---------------- feature transpose (B,C,N) -> (B,N,C) ----------------
__global__ __launch_bounds__(256) void ftrans_kernel(const float* __restrict__ f,
                                                     float* __restrict__ ft)
{
  __shared__ float tile[32][33];
  const int b = blockIdx.z;
  const int n0 = blockIdx.x*32, c0 = blockIdx.y*32;
  const int tx = threadIdx.x & 31, ty = threadIdx.x >> 5; // 32x8
  #pragma unroll
  for (int j=0;j<4;j++)
    tile[ty + j*8][tx] = f[((size_t)b*C_ + (size_t)(c0+ty+j*8))*N_ + n0 + tx];
  __syncthreads();
  #pragma unroll
  for (int j=0;j<4;j++)
    ft[((size_t)b*N_ + (size_t)(n0+ty+j*8))*C_ + c0 + tx] = tile[tx][ty + j*8];
}

// ---------------- weight transpose + zero-pad rows for prefetch ----------------
__global__ void wtrans_kernel(const float* __restrict__ W1, const float* __restrict__ W2,
                              float* __restrict__ W1T, float* __restrict__ W2T)
{
  const int t = threadIdx.x; // 256
  for (int c = 0; c < 261; ++c)
    W1T[c*256 + t] = (c < 259) ? W1[t*259 + c] : 0.f;
  for (int c = 0; c < 258; ++c)
    W2T[c*256 + t] = (c < 256) ? W2[t*256 + c] : 0.f;
}

// ---------------- cylinder query: one wave per (b,p), ordered first-64 ----------------
__global__ __launch_bounds__(256) void query_kernel(const float* __restrict__ xyz,
                                                    const float* __restrict__ rot,
                                                    const float* __restrict__ newXyz,
                                                    int* __restrict__ sIdx,
                                                    float* __restrict__ sRot)
{
  const int lane = threadIdx.x & 63;
  const int bp = blockIdx.x * 4 + (threadIdx.x >> 6);
  const int b = bp >> 10;
  const float* xb = xyz + (size_t)b*N_*3;
  const float* r9 = rot + (size_t)bp*9;
  const float R0=r9[0],R1=r9[1],R2=r9[2],R3=r9[3],R4=r9[4],R5=r9[5],R6=r9[6],R7=r9[7],R8=r9[8];
  const float nx=newXyz[bp*3+0], ny=newXyz[bp*3+1], nz=newXyz[bp*3+2];
  const float thr = R2;   // replicate the reference's r2-shadowing bug
  int* oI = sIdx + (size_t)bp*S_;
  float* oR = sRot + (size_t)bp*3*S_;
  int filled = 0;
  float p0r0=0.f, p0r1=0.f, p0r2=0.f;
  for (int base = 0; base < N_; base += 64){
    const int n = base + lane;
    const float dx = rn_sub(xb[n*3+0], nx);
    const float dy = rn_sub(xb[n*3+1], ny);
    const float dz = rn_sub(xb[n*3+2], nz);
    const float r0 = rn_add(rn_add(rn_mul(dx,R0), rn_mul(dy,R3)), rn_mul(dz,R6));
    const float r1 = rn_add(rn_add(rn_mul(dx,R1), rn_mul(dy,R4)), rn_mul(dz,R7));
    const float r2 = rn_add(rn_add(rn_mul(dx,R2), rn_mul(dy,R5)), rn_mul(dz,R8));
    if (base == 0){
      p0r0 = __shfl(r0, 0, 64); p0r1 = __shfl(r1, 0, 64); p0r2 = __shfl(r2, 0, 64);
    }
    const float d2 = rn_add(rn_mul(r1,r1), rn_mul(r2,r2));
    const bool m = (d2 < thr) & (r0 > -0.02f) & (r0 < 0.04f);
    const unsigned long long bal = __ballot(m);
    const int before = (int)__popcll(bal & ((1ull << lane) - 1ull));
    const int slot = filled + before;
    if (m && slot < S_){
      oI[slot] = n;
      oR[slot] = r0; oR[S_+slot] = r1; oR[2*S_+slot] = r2;
    }
    filled += (int)__popcll(bal);
    if (filled >= S_) break;
  }
  if (filled < S_){
    const int slot = filled + lane;
    if (slot < S_){
      oI[slot] = 0;
      oR[slot] = p0r0; oR[S_+slot] = p0r1; oR[2*S_+slot] = p0r2;
    }
  }
}

// ---------------- fused gather + MLP(259->256->256) + max over S ----------------
__global__ __launch_bounds__(256) void mlp_kernel(const float* __restrict__ featT,
    const int* __restrict__ sIdx, const float* __restrict__ sRot,
    const float* __restrict__ W1T, const float* __restrict__ b1,
    const float* __restrict__ W2T, const float* __restrict__ b2,
    float* __restrict__ out)
{
  __shared__ __align__(16) float Xs[CIN_*XST];
  __shared__ __align__(16) float Hs[O1_*XST];
  __shared__ int sI[S_];
  const int t = threadIdx.x;
  const int bp = blockIdx.x;
  const int b = bp >> 10, p = bp & 1023;
  if (t < S_) sI[t] = sIdx[(size_t)bp*S_ + t];
  if (t < 192){
    const int k = t >> 6, s = t & 63;
    Xs[k*XST + s] = sRot[(size_t)bp*192 + k*64 + s];
  }
  __syncthreads();
  {
    const int tq = t & 63, sb = t >> 6;
    const float* fb = featT + (size_t)b*N_*C_;
    #pragma unroll 4
    for (int s = sb; s < S_; s += 4){
      const int row = sI[s];
      const float4 v = *(const float4*)(fb + (size_t)row*C_ + tq*4);
      const int cb = 3 + tq*4;
      Xs[(cb+0)*XST + s] = v.x;
      Xs[(cb+1)*XST + s] = v.y;
      Xs[(cb+2)*XST + s] = v.z;
      Xs[(cb+3)*XST + s] = v.w;
    }
  }
  __syncthreads();
  const int o = t;
  float acc[64];
  {
    const float bias = b1[o];
    #pragma unroll
    for (int s=0;s<64;s++) acc[s] = bias;
  }
  {
    float w0 = W1T[0*256 + o];
    float w1 = W1T[1*256 + o];
    for (int c = 0; c < CIN_; ++c){
      const float wn = W1T[(c+2)*256 + o];     // 2-deep prefetch (rows zero-padded)
      const float4* xr = (const float4*)(Xs + c*XST);
      #pragma unroll
      for (int i=0;i<16;i++){
        const float4 xv = xr[i];
        acc[4*i+0] = fmaf(w0, xv.x, acc[4*i+0]);
        acc[4*i+1] = fmaf(w0, xv.y, acc[4*i+1]);
        acc[4*i+2] = fmaf(w0, xv.z, acc[4*i+2]);
        acc[4*i+3] = fmaf(w0, xv.w, acc[4*i+3]);
      }
      w0 = w1; w1 = wn;
    }
  }
  #pragma unroll
  for (int i=0;i<16;i++){
    float4 hv;
    hv.x = fmaxf(acc[4*i+0], 0.f);
    hv.y = fmaxf(acc[4*i+1], 0.f);
    hv.z = fmaxf(acc[4*i+2], 0.f);
    hv.w = fmaxf(acc[4*i+3], 0.f);
    *(float4*)(Hs + o*XST + i*4) = hv;
  }
  __syncthreads();
  {
    const float bias2 = b2[o];
    #pragma unroll
    for (int s=0;s<64;s++) acc[s] = bias2;
  }
  {
    float w0 = W2T[0*256 + o];
    float w1 = W2T[1*256 + o];
    for (int c = 0; c < O1_; ++c){
      const float wn = W2T[(c+2)*256 + o];
      const float4* hr = (const float4*)(Hs + c*XST);
      #pragma unroll
      for (int i=0;i<16;i++){
        const float4 xv = hr[i];
        acc[4*i+0] = fmaf(w0, xv.x, acc[4*i+0]);
        acc[4*i+1] = fmaf(w0, xv.y, acc[4*i+1]);
        acc[4*i+2] = fmaf(w0, xv.z, acc[4*i+2]);
        acc[4*i+3] = fmaf(w0, xv.w, acc[4*i+3]);
      }
      w0 = w1; w1 = wn;
    }
  }
  float mx = acc[0];
  #pragma unroll
  for (int s=1;s<64;s++) mx = fmaxf(mx, acc[s]);
  mx = fmaxf(mx, 0.f);
  out[((size_t)b*O1_ + o)*P_ + p] = mx;
}

extern "C" void kernel_launch(void* const* d_in, const int* in_sizes, int n_in,
                              void* d_out, int out_size, void* d_ws, size_t ws_size,
                              hipStream_t stream)
{
  const float* xyz  = (const float*)d_in[0];
  const float* feat = (const float*)d_in[1];
  const float* rot  = (const float*)d_in[2];
  const float* W1   = (const float*)d_in[3];
  const float* b1   = (const float*)d_in[4];
  const float* W2   = (const float*)d_in[5];
  const float* b2   = (const float*)d_in[6];
  float* out = (float*)d_out;

  char* ws = (char*)d_ws;
  float* featT  = (float*)(ws);
  size_t off = (size_t)B_*N_*C_*4;                                  // 16.78 MB
  float* newXyz = (float*)(ws + off); off += (size_t)B_*P_*3*4;     // 48 KB
  int*   sIdx   = (int*)  (ws + off); off += (size_t)B_*P_*S_*4;    // 1 MB
  float* sRot   = (float*)(ws + off); off += (size_t)B_*P_*3*S_*4;  // 3 MB
  float* W1T    = (float*)(ws + off); off += (size_t)261*256*4;
  float* W2T    = (float*)(ws + off); off += (size_t)258*256*4;
  (void)ws_size; (void)in_sizes; (void)n_in; (void)out_size;

  hipLaunchKernelGGL(fps_kernel,    dim3(B_),                dim3(1024), 0, stream, xyz, newXyz);
  hipLaunchKernelGGL(ftrans_kernel, dim3(N_/32, C_/32, B_),  dim3(256),  0, stream, feat, featT);
  hipLaunchKernelGGL(wtrans_kernel, dim3(1),                 dim3(256),  0, stream, W1, W2, W1T, W2T);
  hipLaunchKernelGGL(query_kernel,  dim3(B_*P_/4),           dim3(256),  0, stream, xyz, rot, newXyz, sIdx, sRot);
  hipLaunchKernelGGL(mlp_kernel,    dim3(B_*P_),             dim3(256),  0, stream,
                     featT, sIdx, sRot, W1T, b1, W2T, b2, out);
}

// Round 2
// 1258.335 us; speedup vs baseline: 2.2946x; 2.2946x over previous
//
#include <hip/hip_runtime.h>
#include <hip/hip_bf16.h>

#define B_ 4
#define N_ 4096
#define C_ 256
#define P_ 1024
#define S_ 64
#define HST 264   // H LDS k-stride (bf16 elems); 528B rows -> 2-way (free) frag reads

typedef __attribute__((ext_vector_type(8))) short short8;
typedef __attribute__((ext_vector_type(4))) float f32x4;

__device__ __forceinline__ float rn_mul(float a, float b){ return __fmul_rn(a,b); }
__device__ __forceinline__ float rn_add(float a, float b){ return __fadd_rn(a,b); }
__device__ __forceinline__ float rn_sub(float a, float b){ return __fsub_rn(a,b); }

__device__ __forceinline__ unsigned short f2bf(float x){ // RNE f32->bf16
  union { float f; unsigned u; } v; v.f = x;
  unsigned r = v.u + 0x7fffu + ((v.u >> 16) & 1u);
  return (unsigned short)(r >> 16);
}

__device__ __forceinline__ unsigned long long shflxor_u64(unsigned long long v, int m){
  unsigned lo = (unsigned)__shfl_xor((int)(unsigned)(v & 0xFFFFFFFFull), m, 64);
  unsigned hi = (unsigned)__shfl_xor((int)(unsigned)(v >> 32), m, 64);
  return ((unsigned long long)hi << 32) | (unsigned long long)lo;
}

// ---------------- FPS: one block per batch, exact fp32 semantics (unchanged) ----------------
__global__ __launch_bounds__(1024) void fps_kernel(const float* __restrict__ xyz,
                                                   float* __restrict__ newXyz)
{
  const int b = blockIdx.x;
  const int t = threadIdx.x;
  const int lane = t & 63, wid = t >> 6;
  __shared__ float xl[N_*3];
  __shared__ unsigned long long wred[16];
  __shared__ int sFar;
  const float* xb = xyz + (size_t)b*N_*3;
  for (int i = t; i < N_*3; i += 1024) xl[i] = xb[i];
  __syncthreads();
  float px[4], py[4], pz[4], dist[4];
  #pragma unroll
  for (int j=0;j<4;j++){
    int n = t*4 + j;
    px[j] = xl[n*3+0]; py[j] = xl[n*3+1]; pz[j] = xl[n*3+2];
    dist[j] = 1e10f;
  }
  int far = 0;
  for (int it=0; it<P_; ++it){
    float cx = xl[far*3+0], cy = xl[far*3+1], cz = xl[far*3+2];
    if (t == 0){
      float* nz = newXyz + ((size_t)b*P_ + it)*3;
      nz[0]=cx; nz[1]=cy; nz[2]=cz;
    }
    unsigned long long best = 0;
    #pragma unroll
    for (int j=0;j<4;j++){
      float dx = rn_sub(px[j],cx), dy = rn_sub(py[j],cy), dz = rn_sub(pz[j],cz);
      float d = rn_add(rn_add(rn_mul(dx,dx), rn_mul(dy,dy)), rn_mul(dz,dz));
      float nd = fminf(dist[j], d);
      dist[j] = nd;
      unsigned long long pk = ((unsigned long long)__float_as_uint(nd) << 32)
                            | (unsigned long long)(unsigned)(~(unsigned)(t*4+j));
      best = pk > best ? pk : best;
    }
    #pragma unroll
    for (int m = 32; m >= 1; m >>= 1){
      unsigned long long o = shflxor_u64(best, m);
      best = o > best ? o : best;
    }
    if (lane == 0) wred[wid] = best;
    __syncthreads();
    if (t < 64){
      unsigned long long v = wred[t & 15];
      #pragma unroll
      for (int m = 8; m >= 1; m >>= 1){
        unsigned long long o = shflxor_u64(v, m);
        v = o > v ? o : v;
      }
      if (t == 0) sFar = (int)(~(unsigned)(v & 0xFFFFFFFFull));
    }
    __syncthreads();
    far = sFar;
  }
}

// ---------------- feature transpose (B,C,N) f32 -> (B,N,C) bf16 ----------------
__global__ __launch_bounds__(256) void ftrans_kernel(const float* __restrict__ f,
                                                     unsigned short* __restrict__ ft)
{
  __shared__ float tile[32][33];
  const int b = blockIdx.z;
  const int n0 = blockIdx.x*32, c0 = blockIdx.y*32;
  const int tx = threadIdx.x & 31, ty = threadIdx.x >> 5; // 32x8
  #pragma unroll
  for (int j=0;j<4;j++)
    tile[ty + j*8][tx] = f[((size_t)b*C_ + (size_t)(c0+ty+j*8))*N_ + n0 + tx];
  __syncthreads();
  #pragma unroll
  for (int j=0;j<4;j++)
    ft[((size_t)b*N_ + (size_t)(n0+ty+j*8))*C_ + c0 + tx] = f2bf(tile[tx][ty + j*8]);
}

// ---------------- weight prep: bf16, features-first permutation, zero pad ----------------
// Wp1[o][k], k in [0,288): k<256 -> W1[o][3+k] (features), k=256..258 -> W1[o][k-256] (xyz), else 0
// Wp2[o][k], k in [0,256)
__global__ __launch_bounds__(256) void wprep_kernel(const float* __restrict__ W1,
                                                    const float* __restrict__ W2,
                                                    unsigned short* __restrict__ Wp1,
                                                    unsigned short* __restrict__ Wp2)
{
  const int o = blockIdx.x, t = threadIdx.x;
  Wp1[o*288 + t] = f2bf(W1[o*259 + 3 + t]);
  if (t < 32){
    float v = (t < 3) ? W1[o*259 + t] : 0.f;
    Wp1[o*288 + 256 + t] = f2bf(v);
  }
  Wp2[o*256 + t] = f2bf(W2[o*256 + t]);
}

// ---------------- cylinder query: one wave per (b,p), ordered first-64 (unchanged) ----------------
__global__ __launch_bounds__(256) void query_kernel(const float* __restrict__ xyz,
                                                    const float* __restrict__ rot,
                                                    const float* __restrict__ newXyz,
                                                    int* __restrict__ sIdx,
                                                    float* __restrict__ sRot)
{
  const int lane = threadIdx.x & 63;
  const int bp = blockIdx.x * 4 + (threadIdx.x >> 6);
  const int b = bp >> 10;
  const float* xb = xyz + (size_t)b*N_*3;
  const float* r9 = rot + (size_t)bp*9;
  const float R0=r9[0],R1=r9[1],R2=r9[2],R3=r9[3],R4=r9[4],R5=r9[5],R6=r9[6],R7=r9[7],R8=r9[8];
  const float nx=newXyz[bp*3+0], ny=newXyz[bp*3+1], nz=newXyz[bp*3+2];
  const float thr = R2;   // replicate the reference's r2-shadowing bug
  int* oI = sIdx + (size_t)bp*S_;
  float* oR = sRot + (size_t)bp*3*S_;
  int filled = 0;
  float p0r0=0.f, p0r1=0.f, p0r2=0.f;
  for (int base = 0; base < N_; base += 64){
    const int n = base + lane;
    const float dx = rn_sub(xb[n*3+0], nx);
    const float dy = rn_sub(xb[n*3+1], ny);
    const float dz = rn_sub(xb[n*3+2], nz);
    const float r0 = rn_add(rn_add(rn_mul(dx,R0), rn_mul(dy,R3)), rn_mul(dz,R6));
    const float r1 = rn_add(rn_add(rn_mul(dx,R1), rn_mul(dy,R4)), rn_mul(dz,R7));
    const float r2 = rn_add(rn_add(rn_mul(dx,R2), rn_mul(dy,R5)), rn_mul(dz,R8));
    if (base == 0){
      p0r0 = __shfl(r0, 0, 64); p0r1 = __shfl(r1, 0, 64); p0r2 = __shfl(r2, 0, 64);
    }
    const float d2 = rn_add(rn_mul(r1,r1), rn_mul(r2,r2));
    const bool m = (d2 < thr) & (r0 > -0.02f) & (r0 < 0.04f);
    const unsigned long long bal = __ballot(m);
    const int before = (int)__popcll(bal & ((1ull << lane) - 1ull));
    const int slot = filled + before;
    if (m && slot < S_){
      oI[slot] = n;
      oR[slot] = r0; oR[S_+slot] = r1; oR[2*S_+slot] = r2;
    }
    filled += (int)__popcll(bal);
    if (filled >= S_) break;
  }
  if (filled < S_){
    const int slot = filled + lane;
    if (slot < S_){
      oI[slot] = 0;
      oR[slot] = p0r0; oR[S_+slot] = p0r1; oR[2*S_+slot] = p0r2;
    }
  }
}

// ---------------- MFMA MLP: per (b,p): out = maxpool_s relu(W2 relu(W1 X + b1) + b2) ----------------
// 4 waves; wave w owns output rows [w*64, w*64+64), all 64 s.
// A-frags (W rows) streamed from global (L2-resident); B-frags (gathered X rows) from global;
// H staged in LDS [s][o] bf16 (stride HST) between layers.
__global__ __launch_bounds__(256) void mlp_kernel(
    const unsigned short* __restrict__ featT, // (B,N,C) bf16
    const int* __restrict__ sIdx,
    const float* __restrict__ sRot,
    const unsigned short* __restrict__ Wp1,   // [256][288] bf16
    const float* __restrict__ b1,
    const unsigned short* __restrict__ Wp2,   // [256][256] bf16
    const float* __restrict__ b2,
    float* __restrict__ out)
{
  __shared__ unsigned short Hlds[64*HST];
  const int bid = blockIdx.x;
  const int bp = (bid & 7) * 512 + (bid >> 3);  // XCD-chunked swizzle (4096 % 8 == 0)
  const int b = bp >> 10, p = bp & 1023;
  const int t = threadIdx.x;
  const int w = t >> 6, l = t & 63;
  const int l15 = l & 15, q = l >> 4;

  // per-lane gathered-row pointers + rot values for the 4 s-tiles
  const unsigned short* rowp[4];
  float rot0[4], rot1[4], rot2[4];
  #pragma unroll
  for (int st=0; st<4; ++st){
    const int s = st*16 + l15;
    const int row = sIdx[(size_t)bp*S_ + s];
    rowp[st] = featT + ((size_t)b*N_ + row)*C_;
    rot0[st] = sRot[(size_t)bp*192 + 0*64 + s];
    rot1[st] = sRot[(size_t)bp*192 + 1*64 + s];
    rot2[st] = sRot[(size_t)bp*192 + 2*64 + s];
  }

  f32x4 acc[4][4];
  #pragma unroll
  for (int at=0; at<4; ++at){
    const float4 bv = *(const float4*)(b1 + w*64 + at*16 + q*4);
    #pragma unroll
    for (int st=0; st<4; ++st){
      acc[at][st][0]=bv.x; acc[at][st][1]=bv.y; acc[at][st][2]=bv.z; acc[at][st][3]=bv.w;
    }
  }

  // ---- layer 1: K = 288 (8 feature K-steps + 1 rot/pad K-step) ----
  const unsigned short* wb1 = Wp1 + (size_t)(w*64 + l15)*288 + q*8;
  #pragma unroll
  for (int ks=0; ks<8; ++ks){
    short8 a[4], x[4];
    #pragma unroll
    for (int at=0; at<4; ++at) a[at] = *(const short8*)(wb1 + at*16*288 + ks*32);
    #pragma unroll
    for (int st=0; st<4; ++st) x[st] = *(const short8*)(rowp[st] + ks*32 + q*8);
    #pragma unroll
    for (int at=0; at<4; ++at)
      #pragma unroll
      for (int st=0; st<4; ++st)
        acc[at][st] = __builtin_amdgcn_mfma_f32_16x16x32_bf16(a[at], x[st], acc[at][st], 0,0,0);
  }
  { // K-step 8: k=256..258 are rot_d, k>=259 zero
    short8 a[4], x[4];
    #pragma unroll
    for (int at=0; at<4; ++at) a[at] = *(const short8*)(wb1 + at*16*288 + 8*32);
    #pragma unroll
    for (int st=0; st<4; ++st){
      short8 v = (short8){0,0,0,0,0,0,0,0};
      if (q == 0){
        v[0] = (short)f2bf(rot0[st]);
        v[1] = (short)f2bf(rot1[st]);
        v[2] = (short)f2bf(rot2[st]);
      }
      x[st] = v;
    }
    #pragma unroll
    for (int at=0; at<4; ++at)
      #pragma unroll
      for (int st=0; st<4; ++st)
        acc[at][st] = __builtin_amdgcn_mfma_f32_16x16x32_bf16(a[at], x[st], acc[at][st], 0,0,0);
  }

  // ---- relu -> bf16 -> Hlds[s][o] (lane holds 4 consecutive o per tile -> one b64 write) ----
  #pragma unroll
  for (int at=0; at<4; ++at)
    #pragma unroll
    for (int st=0; st<4; ++st){
      const int s = st*16 + l15;
      const int o = w*64 + at*16 + q*4;
      const unsigned h0 = f2bf(fmaxf(acc[at][st][0], 0.f));
      const unsigned h1 = f2bf(fmaxf(acc[at][st][1], 0.f));
      const unsigned h2 = f2bf(fmaxf(acc[at][st][2], 0.f));
      const unsigned h3 = f2bf(fmaxf(acc[at][st][3], 0.f));
      uint2 u; u.x = h0 | (h1 << 16); u.y = h2 | (h3 << 16);
      *(uint2*)&Hlds[s*HST + o] = u;
    }
  __syncthreads();

  // ---- layer 2: K = 256, B-frags from Hlds ----
  #pragma unroll
  for (int at=0; at<4; ++at){
    const float4 bv = *(const float4*)(b2 + w*64 + at*16 + q*4);
    #pragma unroll
    for (int st=0; st<4; ++st){
      acc[at][st][0]=bv.x; acc[at][st][1]=bv.y; acc[at][st][2]=bv.z; acc[at][st][3]=bv.w;
    }
  }
  const unsigned short* wb2 = Wp2 + (size_t)(w*64 + l15)*256 + q*8;
  #pragma unroll
  for (int ks=0; ks<8; ++ks){
    short8 a[4], h[4];
    #pragma unroll
    for (int at=0; at<4; ++at) a[at] = *(const short8*)(wb2 + at*16*256 + ks*32);
    #pragma unroll
    for (int st=0; st<4; ++st) h[st] = *(const short8*)&Hlds[(st*16+l15)*HST + ks*32 + q*8];
    #pragma unroll
    for (int at=0; at<4; ++at)
      #pragma unroll
      for (int st=0; st<4; ++st)
        acc[at][st] = __builtin_amdgcn_mfma_f32_16x16x32_bf16(a[at], h[st], acc[at][st], 0,0,0);
  }

  // ---- max over s (4 s-tiles in-thread, then 16-lane xor reduce), relu, store ----
  #pragma unroll
  for (int at=0; at<4; ++at){
    #pragma unroll
    for (int r=0; r<4; ++r){
      float m = fmaxf(fmaxf(acc[at][0][r], acc[at][1][r]),
                      fmaxf(acc[at][2][r], acc[at][3][r]));
      m = fmaxf(m, __shfl_xor(m, 1, 64));
      m = fmaxf(m, __shfl_xor(m, 2, 64));
      m = fmaxf(m, __shfl_xor(m, 4, 64));
      m = fmaxf(m, __shfl_xor(m, 8, 64));
      m = fmaxf(m, 0.f);
      if (l15 == 0){
        const int o = w*64 + at*16 + q*4 + r;
        out[((size_t)b*256 + o)*P_ + p] = m;
      }
    }
  }
}

extern "C" void kernel_launch(void* const* d_in, const int* in_sizes, int n_in,
                              void* d_out, int out_size, void* d_ws, size_t ws_size,
                              hipStream_t stream)
{
  const float* xyz  = (const float*)d_in[0];
  const float* feat = (const float*)d_in[1];
  const float* rot  = (const float*)d_in[2];
  const float* W1   = (const float*)d_in[3];
  const float* b1   = (const float*)d_in[4];
  const float* W2   = (const float*)d_in[5];
  const float* b2   = (const float*)d_in[6];
  float* out = (float*)d_out;

  char* ws = (char*)d_ws;
  unsigned short* featT = (unsigned short*)(ws);
  size_t off = (size_t)B_*N_*C_*2;                                   // 8.39 MB
  float* newXyz = (float*)(ws + off); off += (size_t)B_*P_*3*4;      // 48 KB
  int*   sIdx   = (int*)  (ws + off); off += (size_t)B_*P_*S_*4;     // 1 MB
  float* sRot   = (float*)(ws + off); off += (size_t)B_*P_*3*S_*4;   // 3 MB
  unsigned short* Wp1 = (unsigned short*)(ws + off); off += (size_t)256*288*2;
  unsigned short* Wp2 = (unsigned short*)(ws + off); off += (size_t)256*256*2;
  (void)ws_size; (void)in_sizes; (void)n_in; (void)out_size;

  hipLaunchKernelGGL(fps_kernel,    dim3(B_),                dim3(1024), 0, stream, xyz, newXyz);
  hipLaunchKernelGGL(ftrans_kernel, dim3(N_/32, C_/32, B_),  dim3(256),  0, stream, feat, featT);
  hipLaunchKernelGGL(wprep_kernel,  dim3(256),               dim3(256),  0, stream, W1, W2, Wp1, Wp2);
  hipLaunchKernelGGL(query_kernel,  dim3(B_*P_/4),           dim3(256),  0, stream, xyz, rot, newXyz, sIdx, sRot);
  hipLaunchKernelGGL(mlp_kernel,    dim3(B_*P_),             dim3(256),  0, stream,
                     featT, sIdx, sRot, Wp1, b1, Wp2, b2, out);
}

// Round 3
// 965.595 us; speedup vs baseline: 2.9903x; 1.3032x over previous
//
#include <hip/hip_runtime.h>
#include <hip/hip_bf16.h>

#define B_ 4
#define N_ 4096
#define C_ 256
#define P_ 1024
#define S_ 64
#define HST 264   // H LDS k-stride (bf16 elems); 528B rows -> 2-way (free) frag reads

typedef __attribute__((ext_vector_type(8))) short short8;
typedef __attribute__((ext_vector_type(4))) float f32x4;

__device__ __forceinline__ float rn_mul(float a, float b){ return __fmul_rn(a,b); }
__device__ __forceinline__ float rn_add(float a, float b){ return __fadd_rn(a,b); }
__device__ __forceinline__ float rn_sub(float a, float b){ return __fsub_rn(a,b); }

__device__ __forceinline__ unsigned short f2bf(float x){ // RNE f32->bf16
  union { float f; unsigned u; } v; v.f = x;
  unsigned r = v.u + 0x7fffu + ((v.u >> 16) & 1u);
  return (unsigned short)(r >> 16);
}

// ---------------- FPS: one block per batch; u32 value-reduce + ballot index recovery ----------------
// Exact fp32 semantics for distances (non-fused _rn chain, left-fold), argmax with
// first-occurrence tie-break reproduced exactly:
//  - lane-local serial keep-first over its 8 ascending indices,
//  - cross-lane: lowest lane among wave-max holders (lanes own ascending ranges),
//  - cross-wave: serial keep-first scan over ascending wave ids.
__global__ __launch_bounds__(512) void fps_kernel(const float* __restrict__ xyz,
                                                  float* __restrict__ newXyz)
{
  const int b = blockIdx.x;
  const int t = threadIdx.x;            // 0..511
  const int lane = t & 63, w = t >> 6;  // 8 waves
  __shared__ float xl[N_*3];
  __shared__ float cv[2][8];
  __shared__ int   ci[2][8];
  const float* xb = xyz + (size_t)b*N_*3;
  for (int i = t; i < N_*3; i += 512) xl[i] = xb[i];
  __syncthreads();
  float px[8], py[8], pz[8], dist[8];
  #pragma unroll
  for (int j=0;j<8;j++){
    const int n = t*8 + j;
    px[j] = xl[n*3+0]; py[j] = xl[n*3+1]; pz[j] = xl[n*3+2];
    dist[j] = 1e10f;
  }
  int far = 0;
  for (int it=0; it<P_; ++it){
    const float cx = xl[far*3+0], cy = xl[far*3+1], cz = xl[far*3+2];
    if (t == 0){
      float* nz = newXyz + ((size_t)b*P_ + it)*3;
      nz[0]=cx; nz[1]=cy; nz[2]=cz;
    }
    float bestv = -1.f; int bestj = 0;
    #pragma unroll
    for (int j=0;j<8;j++){
      const float dx = rn_sub(px[j],cx), dy = rn_sub(py[j],cy), dz = rn_sub(pz[j],cz);
      const float d  = rn_add(rn_add(rn_mul(dx,dx), rn_mul(dy,dy)), rn_mul(dz,dz));
      const float nd = fminf(dist[j], d);
      dist[j] = nd;
      if (nd > bestv){ bestv = nd; bestj = j; }   // strict > keeps first (lowest j)
    }
    const int bestidx = t*8 + bestj;
    // wave-wide max of value only (f32 >= 0)
    float m = bestv;
    #pragma unroll
    for (int s=1; s<64; s<<=1) m = fmaxf(m, __shfl_xor(m, s, 64));
    const unsigned long long bal = __ballot(bestv == m);
    const int winlane = __ffsll((long long)bal) - 1;   // lowest lane = lowest index
    const int widx = __shfl(bestidx, winlane, 64);
    const int pb = it & 1;                              // double buffer (kills WAR)
    if (lane == 0){ cv[pb][w] = m; ci[pb][w] = widx; }
    __syncthreads();
    // every wave scans the 8 candidates (keep-first on tie, ascending wave id)
    float fv = cv[pb][0]; int fi = ci[pb][0];
    #pragma unroll
    for (int k=1;k<8;k++){
      const float v2 = cv[pb][k]; const int i2 = ci[pb][k];
      const bool gt = v2 > fv;
      fv = gt ? v2 : fv;
      fi = gt ? i2 : fi;
    }
    far = fi;
  }
}

// ---------------- feature transpose (B,C,N) f32 -> (B,N,C) bf16 ----------------
__global__ __launch_bounds__(256) void ftrans_kernel(const float* __restrict__ f,
                                                     unsigned short* __restrict__ ft)
{
  __shared__ float tile[32][33];
  const int b = blockIdx.z;
  const int n0 = blockIdx.x*32, c0 = blockIdx.y*32;
  const int tx = threadIdx.x & 31, ty = threadIdx.x >> 5; // 32x8
  #pragma unroll
  for (int j=0;j<4;j++)
    tile[ty + j*8][tx] = f[((size_t)b*C_ + (size_t)(c0+ty+j*8))*N_ + n0 + tx];
  __syncthreads();
  #pragma unroll
  for (int j=0;j<4;j++)
    ft[((size_t)b*N_ + (size_t)(n0+ty+j*8))*C_ + c0 + tx] = f2bf(tile[tx][ty + j*8]);
}

// ---------------- weight prep: bf16, features-first permutation, zero pad ----------------
__global__ __launch_bounds__(256) void wprep_kernel(const float* __restrict__ W1,
                                                    const float* __restrict__ W2,
                                                    unsigned short* __restrict__ Wp1,
                                                    unsigned short* __restrict__ Wp2)
{
  const int o = blockIdx.x, t = threadIdx.x;
  Wp1[o*288 + t] = f2bf(W1[o*259 + 3 + t]);
  if (t < 32){
    float v = (t < 3) ? W1[o*259 + t] : 0.f;
    Wp1[o*288 + 256 + t] = f2bf(v);
  }
  Wp2[o*256 + t] = f2bf(W2[o*256 + t]);
}

// ---------------- cylinder query: one wave per (b,p), ordered first-64 ----------------
__global__ __launch_bounds__(256) void query_kernel(const float* __restrict__ xyz,
                                                    const float* __restrict__ rot,
                                                    const float* __restrict__ newXyz,
                                                    int* __restrict__ sIdx,
                                                    float* __restrict__ sRot)
{
  const int lane = threadIdx.x & 63;
  const int bp = blockIdx.x * 4 + (threadIdx.x >> 6);
  const int b = bp >> 10;
  const float* xb = xyz + (size_t)b*N_*3;
  const float* r9 = rot + (size_t)bp*9;
  const float R0=r9[0],R1=r9[1],R2=r9[2],R3=r9[3],R4=r9[4],R5=r9[5],R6=r9[6],R7=r9[7],R8=r9[8];
  const float nx=newXyz[bp*3+0], ny=newXyz[bp*3+1], nz=newXyz[bp*3+2];
  const float thr = R2;   // replicate the reference's r2-shadowing bug
  int* oI = sIdx + (size_t)bp*S_;
  float* oR = sRot + (size_t)bp*3*S_;
  int filled = 0;
  float p0r0=0.f, p0r1=0.f, p0r2=0.f;
  for (int base = 0; base < N_; base += 64){
    const int n = base + lane;
    const float dx = rn_sub(xb[n*3+0], nx);
    const float dy = rn_sub(xb[n*3+1], ny);
    const float dz = rn_sub(xb[n*3+2], nz);
    const float r0 = rn_add(rn_add(rn_mul(dx,R0), rn_mul(dy,R3)), rn_mul(dz,R6));
    const float r1 = rn_add(rn_add(rn_mul(dx,R1), rn_mul(dy,R4)), rn_mul(dz,R7));
    const float r2 = rn_add(rn_add(rn_mul(dx,R2), rn_mul(dy,R5)), rn_mul(dz,R8));
    if (base == 0){
      p0r0 = __shfl(r0, 0, 64); p0r1 = __shfl(r1, 0, 64); p0r2 = __shfl(r2, 0, 64);
    }
    const float d2 = rn_add(rn_mul(r1,r1), rn_mul(r2,r2));
    const bool m = (d2 < thr) & (r0 > -0.02f) & (r0 < 0.04f);
    const unsigned long long bal = __ballot(m);
    const int before = (int)__popcll(bal & ((1ull << lane) - 1ull));
    const int slot = filled + before;
    if (m && slot < S_){
      oI[slot] = n;
      oR[slot] = r0; oR[S_+slot] = r1; oR[2*S_+slot] = r2;
    }
    filled += (int)__popcll(bal);
    if (filled >= S_) break;
  }
  if (filled < S_){
    const int slot = filled + lane;
    if (slot < S_){
      oI[slot] = 0;
      oR[slot] = p0r0; oR[S_+slot] = p0r1; oR[2*S_+slot] = p0r2;
    }
  }
}

// ---------------- MFMA MLP: per (b,p): out = maxpool_s relu(W2 relu(W1 X + b1) + b2) ----------------
__global__ __launch_bounds__(256) void mlp_kernel(
    const unsigned short* __restrict__ featT, // (B,N,C) bf16
    const int* __restrict__ sIdx,
    const float* __restrict__ sRot,
    const unsigned short* __restrict__ Wp1,   // [256][288] bf16
    const float* __restrict__ b1,
    const unsigned short* __restrict__ Wp2,   // [256][256] bf16
    const float* __restrict__ b2,
    float* __restrict__ out)
{
  __shared__ unsigned short Hlds[64*HST];
  const int bid = blockIdx.x;
  const int bp = (bid & 7) * 512 + (bid >> 3);  // XCD-chunked swizzle (4096 % 8 == 0)
  const int b = bp >> 10, p = bp & 1023;
  const int t = threadIdx.x;
  const int w = t >> 6, l = t & 63;
  const int l15 = l & 15, q = l >> 4;

  const unsigned short* rowp[4];
  float rot0[4], rot1[4], rot2[4];
  #pragma unroll
  for (int st=0; st<4; ++st){
    const int s = st*16 + l15;
    const int row = sIdx[(size_t)bp*S_ + s];
    rowp[st] = featT + ((size_t)b*N_ + row)*C_;
    rot0[st] = sRot[(size_t)bp*192 + 0*64 + s];
    rot1[st] = sRot[(size_t)bp*192 + 1*64 + s];
    rot2[st] = sRot[(size_t)bp*192 + 2*64 + s];
  }

  f32x4 acc[4][4];
  #pragma unroll
  for (int at=0; at<4; ++at){
    const float4 bv = *(const float4*)(b1 + w*64 + at*16 + q*4);
    #pragma unroll
    for (int st=0; st<4; ++st){
      acc[at][st][0]=bv.x; acc[at][st][1]=bv.y; acc[at][st][2]=bv.z; acc[at][st][3]=bv.w;
    }
  }

  // ---- layer 1: K = 288 (8 feature K-steps + 1 rot/pad K-step) ----
  const unsigned short* wb1 = Wp1 + (size_t)(w*64 + l15)*288 + q*8;
  #pragma unroll
  for (int ks=0; ks<8; ++ks){
    short8 a[4], x[4];
    #pragma unroll
    for (int at=0; at<4; ++at) a[at] = *(const short8*)(wb1 + at*16*288 + ks*32);
    #pragma unroll
    for (int st=0; st<4; ++st) x[st] = *(const short8*)(rowp[st] + ks*32 + q*8);
    #pragma unroll
    for (int at=0; at<4; ++at)
      #pragma unroll
      for (int st=0; st<4; ++st)
        acc[at][st] = __builtin_amdgcn_mfma_f32_16x16x32_bf16(a[at], x[st], acc[at][st], 0,0,0);
  }
  { // K-step 8: k=256..258 are rot_d, k>=259 zero
    short8 a[4], x[4];
    #pragma unroll
    for (int at=0; at<4; ++at) a[at] = *(const short8*)(wb1 + at*16*288 + 8*32);
    #pragma unroll
    for (int st=0; st<4; ++st){
      short8 v = (short8){0,0,0,0,0,0,0,0};
      if (q == 0){
        v[0] = (short)f2bf(rot0[st]);
        v[1] = (short)f2bf(rot1[st]);
        v[2] = (short)f2bf(rot2[st]);
      }
      x[st] = v;
    }
    #pragma unroll
    for (int at=0; at<4; ++at)
      #pragma unroll
      for (int st=0; st<4; ++st)
        acc[at][st] = __builtin_amdgcn_mfma_f32_16x16x32_bf16(a[at], x[st], acc[at][st], 0,0,0);
  }

  // ---- relu -> bf16 -> Hlds[s][o] ----
  #pragma unroll
  for (int at=0; at<4; ++at)
    #pragma unroll
    for (int st=0; st<4; ++st){
      const int s = st*16 + l15;
      const int o = w*64 + at*16 + q*4;
      const unsigned h0 = f2bf(fmaxf(acc[at][st][0], 0.f));
      const unsigned h1 = f2bf(fmaxf(acc[at][st][1], 0.f));
      const unsigned h2 = f2bf(fmaxf(acc[at][st][2], 0.f));
      const unsigned h3 = f2bf(fmaxf(acc[at][st][3], 0.f));
      uint2 u; u.x = h0 | (h1 << 16); u.y = h2 | (h3 << 16);
      *(uint2*)&Hlds[s*HST + o] = u;
    }
  __syncthreads();

  // ---- layer 2: K = 256, B-frags from Hlds ----
  #pragma unroll
  for (int at=0; at<4; ++at){
    const float4 bv = *(const float4*)(b2 + w*64 + at*16 + q*4);
    #pragma unroll
    for (int st=0; st<4; ++st){
      acc[at][st][0]=bv.x; acc[at][st][1]=bv.y; acc[at][st][2]=bv.z; acc[at][st][3]=bv.w;
    }
  }
  const unsigned short* wb2 = Wp2 + (size_t)(w*64 + l15)*256 + q*8;
  #pragma unroll
  for (int ks=0; ks<8; ++ks){
    short8 a[4], h[4];
    #pragma unroll
    for (int at=0; at<4; ++at) a[at] = *(const short8*)(wb2 + at*16*256 + ks*32);
    #pragma unroll
    for (int st=0; st<4; ++st) h[st] = *(const short8*)&Hlds[(st*16+l15)*HST + ks*32 + q*8];
    #pragma unroll
    for (int at=0; at<4; ++at)
      #pragma unroll
      for (int st=0; st<4; ++st)
        acc[at][st] = __builtin_amdgcn_mfma_f32_16x16x32_bf16(a[at], h[st], acc[at][st], 0,0,0);
  }

  // ---- max over s, relu, store ----
  #pragma unroll
  for (int at=0; at<4; ++at){
    #pragma unroll
    for (int r=0; r<4; ++r){
      float m = fmaxf(fmaxf(acc[at][0][r], acc[at][1][r]),
                      fmaxf(acc[at][2][r], acc[at][3][r]));
      m = fmaxf(m, __shfl_xor(m, 1, 64));
      m = fmaxf(m, __shfl_xor(m, 2, 64));
      m = fmaxf(m, __shfl_xor(m, 4, 64));
      m = fmaxf(m, __shfl_xor(m, 8, 64));
      m = fmaxf(m, 0.f);
      if (l15 == 0){
        const int o = w*64 + at*16 + q*4 + r;
        out[((size_t)b*256 + o)*P_ + p] = m;
      }
    }
  }
}

extern "C" void kernel_launch(void* const* d_in, const int* in_sizes, int n_in,
                              void* d_out, int out_size, void* d_ws, size_t ws_size,
                              hipStream_t stream)
{
  const float* xyz  = (const float*)d_in[0];
  const float* feat = (const float*)d_in[1];
  const float* rot  = (const float*)d_in[2];
  const float* W1   = (const float*)d_in[3];
  const float* b1   = (const float*)d_in[4];
  const float* W2   = (const float*)d_in[5];
  const float* b2   = (const float*)d_in[6];
  float* out = (float*)d_out;

  char* ws = (char*)d_ws;
  unsigned short* featT = (unsigned short*)(ws);
  size_t off = (size_t)B_*N_*C_*2;                                   // 8.39 MB
  float* newXyz = (float*)(ws + off); off += (size_t)B_*P_*3*4;      // 48 KB
  int*   sIdx   = (int*)  (ws + off); off += (size_t)B_*P_*S_*4;     // 1 MB
  float* sRot   = (float*)(ws + off); off += (size_t)B_*P_*3*S_*4;   // 3 MB
  unsigned short* Wp1 = (unsigned short*)(ws + off); off += (size_t)256*288*2;
  unsigned short* Wp2 = (unsigned short*)(ws + off); off += (size_t)256*256*2;
  (void)ws_size; (void)in_sizes; (void)n_in; (void)out_size;

  hipLaunchKernelGGL(fps_kernel,    dim3(B_),                dim3(512),  0, stream, xyz, newXyz);
  hipLaunchKernelGGL(ftrans_kernel, dim3(N_/32, C_/32, B_),  dim3(256),  0, stream, feat, featT);
  hipLaunchKernelGGL(wprep_kernel,  dim3(256),               dim3(256),  0, stream, W1, W2, Wp1, Wp2);
  hipLaunchKernelGGL(query_kernel,  dim3(B_*P_/4),           dim3(256),  0, stream, xyz, rot, newXyz, sIdx, sRot);
  hipLaunchKernelGGL(mlp_kernel,    dim3(B_*P_),             dim3(256),  0, stream,
                     featT, sIdx, sRot, Wp1, b1, Wp2, b2, out);
}

// Round 4
// 857.031 us; speedup vs baseline: 3.3691x; 1.1267x over previous
//
#include <hip/hip_runtime.h>
#include <hip/hip_bf16.h>

#define B_ 4
#define N_ 4096
#define C_ 256
#define P_ 1024
#define S_ 64
#define HST 264   // H LDS k-stride (bf16 elems); 528B rows -> 2-way (free) frag reads

typedef __attribute__((ext_vector_type(8))) short short8;
typedef __attribute__((ext_vector_type(4))) float f32x4;

__device__ __forceinline__ float rn_mul(float a, float b){ return __fmul_rn(a,b); }
__device__ __forceinline__ float rn_add(float a, float b){ return __fadd_rn(a,b); }
__device__ __forceinline__ float rn_sub(float a, float b){ return __fsub_rn(a,b); }

__device__ __forceinline__ unsigned short f2bf(float x){ // RNE f32->bf16
  union { float f; unsigned u; } v; v.f = x;
  unsigned r = v.u + 0x7fffu + ((v.u >> 16) & 1u);
  return (unsigned short)(r >> 16);
}

// v_max with a DPP-permuted copy; OOB/disabled lanes contribute 0 (safe: dists >= 0)
#define DPPMAX(m, ctrl) \
  m = fmaxf(m, __int_as_float(__builtin_amdgcn_update_dpp(0, __float_as_int(m), ctrl, 0xF, 0xF, true)))

// ---------------- FPS: one block/batch, 4 waves x 16 pts; DPP value-reduce ----------------
// Exact fp32 distance semantics (_rn chain, left-fold). First-occurrence argmax:
// lane-local keep-first (strict >, ascending j) -> lowest lane of value-match ballot
// (lanes own contiguous ascending ranges) -> ascending-wave keep-first scan.
__global__ __launch_bounds__(256) void fps_kernel(const float* __restrict__ xyz,
                                                  float* __restrict__ newXyz)
{
  const int b = blockIdx.x;
  const int t = threadIdx.x;            // 0..255
  const int lane = t & 63, w = t >> 6;  // 4 waves
  __shared__ float xl[N_*3];
  __shared__ float4 cand[2][4];
  const float* xb = xyz + (size_t)b*N_*3;
  {
    float4* dst = (float4*)xl; const float4* src = (const float4*)xb;
    for (int i = t; i < N_*3/4; i += 256) dst[i] = src[i];
  }
  __syncthreads();
  float px[16], py[16], pz[16], dist[16];
  {
    float buf[48];
    #pragma unroll
    for (int i=0;i<12;i++){
      const float4 v = *(const float4*)&xl[t*48 + i*4];
      buf[i*4+0]=v.x; buf[i*4+1]=v.y; buf[i*4+2]=v.z; buf[i*4+3]=v.w;
    }
    #pragma unroll
    for (int j=0;j<16;j++){
      px[j]=buf[j*3+0]; py[j]=buf[j*3+1]; pz[j]=buf[j*3+2];
      dist[j] = 1e10f;
    }
  }
  float cx = xl[0], cy = xl[1], cz = xl[2];   // farthest_0 = 0
  for (int it=0; it<P_; ++it){
    if (t == 0){
      float* nz = newXyz + ((size_t)b*P_ + it)*3;
      nz[0]=cx; nz[1]=cy; nz[2]=cz;
    }
    float bestv = -1.f; int bestj = 0;
    #pragma unroll
    for (int j=0;j<16;j++){
      const float dx = rn_sub(px[j],cx), dy = rn_sub(py[j],cy), dz = rn_sub(pz[j],cz);
      const float d  = rn_add(rn_add(rn_mul(dx,dx), rn_mul(dy,dy)), rn_mul(dz,dz));
      const float nd = fminf(dist[j], d);
      dist[j] = nd;
      if (nd > bestv){ bestv = nd; bestj = j; }   // strict > keeps first (lowest j)
    }
    // wave max of value only, via DPP (VALU pipe, no LDS)
    float m = bestv;
    DPPMAX(m, 0x111);  // row_shr:1
    DPPMAX(m, 0x112);  // row_shr:2
    DPPMAX(m, 0x114);  // row_shr:4
    DPPMAX(m, 0x118);  // row_shr:8
    DPPMAX(m, 0x142);  // row_bcast:15
    DPPMAX(m, 0x143);  // row_bcast:31
    const float ms = __int_as_float(__builtin_amdgcn_readlane(__float_as_int(m), 63));
    const unsigned long long bal = __ballot(bestv == ms);
    const int winlane = __ffsll((long long)bal) - 1;        // lowest lane = lowest index
    const int widx = __builtin_amdgcn_readlane(t*16 + bestj, winlane) & ~15;
    const int wj   = __builtin_amdgcn_readlane(bestj, winlane);
    const int pb = it & 1;                                   // double buffer (skew <= 1)
    if (lane == 0){
      const float* cp = xl + (size_t)(widx + wj)*3;
      cand[pb][w] = make_float4(ms, cp[0], cp[1], cp[2]);
    }
    __syncthreads();
    // keep-first scan over 4 wave candidates (ascending wave id)
    const float4 c0 = cand[pb][0], c1 = cand[pb][1], c2 = cand[pb][2], c3 = cand[pb][3];
    float fv = c0.x; cx = c0.y; cy = c0.z; cz = c0.w;
    if (c1.x > fv){ fv = c1.x; cx = c1.y; cy = c1.z; cz = c1.w; }
    if (c2.x > fv){ fv = c2.x; cx = c2.y; cy = c2.z; cz = c2.w; }
    if (c3.x > fv){ fv = c3.x; cx = c3.y; cy = c3.z; cz = c3.w; }
  }
}

// ---------------- feature transpose (B,C,N) f32 -> (B,N,C) bf16 ----------------
__global__ __launch_bounds__(256) void ftrans_kernel(const float* __restrict__ f,
                                                     unsigned short* __restrict__ ft)
{
  __shared__ float tile[32][33];
  const int b = blockIdx.z;
  const int n0 = blockIdx.x*32, c0 = blockIdx.y*32;
  const int tx = threadIdx.x & 31, ty = threadIdx.x >> 5; // 32x8
  #pragma unroll
  for (int j=0;j<4;j++)
    tile[ty + j*8][tx] = f[((size_t)b*C_ + (size_t)(c0+ty+j*8))*N_ + n0 + tx];
  __syncthreads();
  #pragma unroll
  for (int j=0;j<4;j++)
    ft[((size_t)b*N_ + (size_t)(n0+ty+j*8))*C_ + c0 + tx] = f2bf(tile[tx][ty + j*8]);
}

// ---------------- weight prep: bf16, features-first permutation, zero pad ----------------
__global__ __launch_bounds__(256) void wprep_kernel(const float* __restrict__ W1,
                                                    const float* __restrict__ W2,
                                                    unsigned short* __restrict__ Wp1,
                                                    unsigned short* __restrict__ Wp2)
{
  const int o = blockIdx.x, t = threadIdx.x;
  Wp1[o*288 + t] = f2bf(W1[o*259 + 3 + t]);
  if (t < 32){
    float v = (t < 3) ? W1[o*259 + t] : 0.f;
    Wp1[o*288 + 256 + t] = f2bf(v);
  }
  Wp2[o*256 + t] = f2bf(W2[o*256 + t]);
}

// ---------------- cylinder query: one wave per (b,p), ordered first-64 ----------------
__global__ __launch_bounds__(256) void query_kernel(const float* __restrict__ xyz,
                                                    const float* __restrict__ rot,
                                                    const float* __restrict__ newXyz,
                                                    int* __restrict__ sIdx,
                                                    float* __restrict__ sRot)
{
  const int lane = threadIdx.x & 63;
  const int bp = blockIdx.x * 4 + (threadIdx.x >> 6);
  const int b = bp >> 10;
  const float* xb = xyz + (size_t)b*N_*3;
  const float* r9 = rot + (size_t)bp*9;
  const float R0=r9[0],R1=r9[1],R2=r9[2],R3=r9[3],R4=r9[4],R5=r9[5],R6=r9[6],R7=r9[7],R8=r9[8];
  const float nx=newXyz[bp*3+0], ny=newXyz[bp*3+1], nz=newXyz[bp*3+2];
  const float thr = R2;   // replicate the reference's r2-shadowing bug
  int* oI = sIdx + (size_t)bp*S_;
  float* oR = sRot + (size_t)bp*3*S_;
  int filled = 0;
  float p0r0=0.f, p0r1=0.f, p0r2=0.f;
  for (int base = 0; base < N_; base += 64){
    const int n = base + lane;
    const float dx = rn_sub(xb[n*3+0], nx);
    const float dy = rn_sub(xb[n*3+1], ny);
    const float dz = rn_sub(xb[n*3+2], nz);
    const float r0 = rn_add(rn_add(rn_mul(dx,R0), rn_mul(dy,R3)), rn_mul(dz,R6));
    const float r1 = rn_add(rn_add(rn_mul(dx,R1), rn_mul(dy,R4)), rn_mul(dz,R7));
    const float r2 = rn_add(rn_add(rn_mul(dx,R2), rn_mul(dy,R5)), rn_mul(dz,R8));
    if (base == 0){
      p0r0 = __shfl(r0, 0, 64); p0r1 = __shfl(r1, 0, 64); p0r2 = __shfl(r2, 0, 64);
    }
    const float d2 = rn_add(rn_mul(r1,r1), rn_mul(r2,r2));
    const bool m = (d2 < thr) & (r0 > -0.02f) & (r0 < 0.04f);
    const unsigned long long bal = __ballot(m);
    const int before = (int)__popcll(bal & ((1ull << lane) - 1ull));
    const int slot = filled + before;
    if (m && slot < S_){
      oI[slot] = n;
      oR[slot] = r0; oR[S_+slot] = r1; oR[2*S_+slot] = r2;
    }
    filled += (int)__popcll(bal);
    if (filled >= S_) break;
  }
  if (filled < S_){
    const int slot = filled + lane;
    if (slot < S_){
      oI[slot] = 0;
      oR[slot] = p0r0; oR[S_+slot] = p0r1; oR[2*S_+slot] = p0r2;
    }
  }
}

// ---------------- MFMA MLP: per (b,p): out = maxpool_s relu(W2 relu(W1 X + b1) + b2) ----------------
__global__ __launch_bounds__(256) void mlp_kernel(
    const unsigned short* __restrict__ featT, // (B,N,C) bf16
    const int* __restrict__ sIdx,
    const float* __restrict__ sRot,
    const unsigned short* __restrict__ Wp1,   // [256][288] bf16
    const float* __restrict__ b1,
    const unsigned short* __restrict__ Wp2,   // [256][256] bf16
    const float* __restrict__ b2,
    float* __restrict__ out)
{
  __shared__ unsigned short Hlds[64*HST];
  const int bid = blockIdx.x;
  const int bp = (bid & 7) * 512 + (bid >> 3);  // XCD-chunked swizzle (4096 % 8 == 0)
  const int b = bp >> 10, p = bp & 1023;
  const int t = threadIdx.x;
  const int w = t >> 6, l = t & 63;
  const int l15 = l & 15, q = l >> 4;

  const unsigned short* rowp[4];
  float rot0[4], rot1[4], rot2[4];
  #pragma unroll
  for (int st=0; st<4; ++st){
    const int s = st*16 + l15;
    const int row = sIdx[(size_t)bp*S_ + s];
    rowp[st] = featT + ((size_t)b*N_ + row)*C_;
    rot0[st] = sRot[(size_t)bp*192 + 0*64 + s];
    rot1[st] = sRot[(size_t)bp*192 + 1*64 + s];
    rot2[st] = sRot[(size_t)bp*192 + 2*64 + s];
  }

  f32x4 acc[4][4];
  #pragma unroll
  for (int at=0; at<4; ++at){
    const float4 bv = *(const float4*)(b1 + w*64 + at*16 + q*4);
    #pragma unroll
    for (int st=0; st<4; ++st){
      acc[at][st][0]=bv.x; acc[at][st][1]=bv.y; acc[at][st][2]=bv.z; acc[at][st][3]=bv.w;
    }
  }

  // ---- layer 1: K = 288 (8 feature K-steps + 1 rot/pad K-step) ----
  const unsigned short* wb1 = Wp1 + (size_t)(w*64 + l15)*288 + q*8;
  #pragma unroll
  for (int ks=0; ks<8; ++ks){
    short8 a[4], x[4];
    #pragma unroll
    for (int at=0; at<4; ++at) a[at] = *(const short8*)(wb1 + at*16*288 + ks*32);
    #pragma unroll
    for (int st=0; st<4; ++st) x[st] = *(const short8*)(rowp[st] + ks*32 + q*8);
    #pragma unroll
    for (int at=0; at<4; ++at)
      #pragma unroll
      for (int st=0; st<4; ++st)
        acc[at][st] = __builtin_amdgcn_mfma_f32_16x16x32_bf16(a[at], x[st], acc[at][st], 0,0,0);
  }
  { // K-step 8: k=256..258 are rot_d, k>=259 zero
    short8 a[4], x[4];
    #pragma unroll
    for (int at=0; at<4; ++at) a[at] = *(const short8*)(wb1 + at*16*288 + 8*32);
    #pragma unroll
    for (int st=0; st<4; ++st){
      short8 v = (short8){0,0,0,0,0,0,0,0};
      if (q == 0){
        v[0] = (short)f2bf(rot0[st]);
        v[1] = (short)f2bf(rot1[st]);
        v[2] = (short)f2bf(rot2[st]);
      }
      x[st] = v;
    }
    #pragma unroll
    for (int at=0; at<4; ++at)
      #pragma unroll
      for (int st=0; st<4; ++st)
        acc[at][st] = __builtin_amdgcn_mfma_f32_16x16x32_bf16(a[at], x[st], acc[at][st], 0,0,0);
  }

  // ---- relu -> bf16 -> Hlds[s][o] ----
  #pragma unroll
  for (int at=0; at<4; ++at)
    #pragma unroll
    for (int st=0; st<4; ++st){
      const int s = st*16 + l15;
      const int o = w*64 + at*16 + q*4;
      const unsigned h0 = f2bf(fmaxf(acc[at][st][0], 0.f));
      const unsigned h1 = f2bf(fmaxf(acc[at][st][1], 0.f));
      const unsigned h2 = f2bf(fmaxf(acc[at][st][2], 0.f));
      const unsigned h3 = f2bf(fmaxf(acc[at][st][3], 0.f));
      uint2 u; u.x = h0 | (h1 << 16); u.y = h2 | (h3 << 16);
      *(uint2*)&Hlds[s*HST + o] = u;
    }
  __syncthreads();

  // ---- layer 2: K = 256, B-frags from Hlds ----
  #pragma unroll
  for (int at=0; at<4; ++at){
    const float4 bv = *(const float4*)(b2 + w*64 + at*16 + q*4);
    #pragma unroll
    for (int st=0; st<4; ++st){
      acc[at][st][0]=bv.x; acc[at][st][1]=bv.y; acc[at][st][2]=bv.z; acc[at][st][3]=bv.w;
    }
  }
  const unsigned short* wb2 = Wp2 + (size_t)(w*64 + l15)*256 + q*8;
  #pragma unroll
  for (int ks=0; ks<8; ++ks){
    short8 a[4], h[4];
    #pragma unroll
    for (int at=0; at<4; ++at) a[at] = *(const short8*)(wb2 + at*16*256 + ks*32);
    #pragma unroll
    for (int st=0; st<4; ++st) h[st] = *(const short8*)&Hlds[(st*16+l15)*HST + ks*32 + q*8];
    #pragma unroll
    for (int at=0; at<4; ++at)
      #pragma unroll
      for (int st=0; st<4; ++st)
        acc[at][st] = __builtin_amdgcn_mfma_f32_16x16x32_bf16(a[at], h[st], acc[at][st], 0,0,0);
  }

  // ---- max over s, relu, store ----
  #pragma unroll
  for (int at=0; at<4; ++at){
    #pragma unroll
    for (int r=0; r<4; ++r){
      float m = fmaxf(fmaxf(acc[at][0][r], acc[at][1][r]),
                      fmaxf(acc[at][2][r], acc[at][3][r]));
      m = fmaxf(m, __shfl_xor(m, 1, 64));
      m = fmaxf(m, __shfl_xor(m, 2, 64));
      m = fmaxf(m, __shfl_xor(m, 4, 64));
      m = fmaxf(m, __shfl_xor(m, 8, 64));
      m = fmaxf(m, 0.f);
      if (l15 == 0){
        const int o = w*64 + at*16 + q*4 + r;
        out[((size_t)b*256 + o)*P_ + p] = m;
      }
    }
  }
}

extern "C" void kernel_launch(void* const* d_in, const int* in_sizes, int n_in,
                              void* d_out, int out_size, void* d_ws, size_t ws_size,
                              hipStream_t stream)
{
  const float* xyz  = (const float*)d_in[0];
  const float* feat = (const float*)d_in[1];
  const float* rot  = (const float*)d_in[2];
  const float* W1   = (const float*)d_in[3];
  const float* b1   = (const float*)d_in[4];
  const float* W2   = (const float*)d_in[5];
  const float* b2   = (const float*)d_in[6];
  float* out = (float*)d_out;

  char* ws = (char*)d_ws;
  unsigned short* featT = (unsigned short*)(ws);
  size_t off = (size_t)B_*N_*C_*2;                                   // 8.39 MB
  float* newXyz = (float*)(ws + off); off += (size_t)B_*P_*3*4;      // 48 KB
  int*   sIdx   = (int*)  (ws + off); off += (size_t)B_*P_*S_*4;     // 1 MB
  float* sRot   = (float*)(ws + off); off += (size_t)B_*P_*3*S_*4;   // 3 MB
  unsigned short* Wp1 = (unsigned short*)(ws + off); off += (size_t)256*288*2;
  unsigned short* Wp2 = (unsigned short*)(ws + off); off += (size_t)256*256*2;
  (void)ws_size; (void)in_sizes; (void)n_in; (void)out_size;

  hipLaunchKernelGGL(fps_kernel,    dim3(B_),                dim3(256),  0, stream, xyz, newXyz);
  hipLaunchKernelGGL(ftrans_kernel, dim3(N_/32, C_/32, B_),  dim3(256),  0, stream, feat, featT);
  hipLaunchKernelGGL(wprep_kernel,  dim3(256),               dim3(256),  0, stream, W1, W2, Wp1, Wp2);
  hipLaunchKernelGGL(query_kernel,  dim3(B_*P_/4),           dim3(256),  0, stream, xyz, rot, newXyz, sIdx, sRot);
  hipLaunchKernelGGL(mlp_kernel,    dim3(B_*P_),             dim3(256),  0, stream,
                     featT, sIdx, sRot, Wp1, b1, Wp2, b2, out);
}